// Round 5
// baseline (384.281 us; speedup 1.0000x reference)
//
#include <hip/hip_runtime.h>

#define OUT_F 11008
#define IN_F  4096
#define NBATCH 8
#define R 4                     // output rows per block
#define BLOCK 256
#define NGR 32                  // groups per row = IN_F/128
#define KITERS (IN_F / (4 * BLOCK))   // 4: each thread covers 4 columns per k-iter

// __launch_bounds__(256,3): 168-VGPR cap. Real footprint ~115 regs
// (acc 32 + idx cur/nxt 32 + w 16 + 4 live float4 x 16 + addr temps).
// (256,4) capped at 128 -> scratch spill -> 10% occupancy (round 4 evidence).
__global__ __launch_bounds__(BLOCK, 3) void pal_linear_kernel(
    const float* __restrict__ x,        // [8, 4096]
    const int*   __restrict__ widx,     // [11008*4096] in [0,16)
    const float* __restrict__ lut,      // [352256, 16] f32 on device
    const float* __restrict__ bias,     // [11008]
    float* __restrict__ out)            // [8, 11008]
{
    __shared__ float lutS[R * NGR * 16];            // 8 KB contiguous slice
    __shared__ float red[BLOCK / 64][R * NBATCH];

    const int tid = threadIdx.x;
    const int o0  = blockIdx.x * R;

    // stage this block's LUT slice (2048 consecutive floats) into LDS
    {
        const float4* src = reinterpret_cast<const float4*>(lut + (size_t)o0 * NGR * 16);
        float4* dst = reinterpret_cast<float4*>(lutS);
#pragma unroll
        for (int i = 0; i < (R * NGR * 16 / 4) / BLOCK; ++i)   // 2 iters
            dst[tid + i * BLOCK] = src[tid + i * BLOCK];
    }
    __syncthreads();

    float acc[R][NBATCH];
#pragma unroll
    for (int r = 0; r < R; ++r)
#pragma unroll
        for (int m = 0; m < NBATCH; ++m) acc[r][m] = 0.0f;

    // 1-deep software pipeline on the 180 MB index stream
    int4 idx_cur[R], idx_nxt[R];
#pragma unroll
    for (int r = 0; r < R; ++r)
        idx_cur[r] = *reinterpret_cast<const int4*>(widx + (size_t)(o0 + r) * IN_F + 4 * tid);

#pragma unroll 1
    for (int k = 0; k < KITERS; ++k) {
        const int c = 4 * (tid + BLOCK * k);

        if (k + 1 < KITERS) {
#pragma unroll
            for (int r = 0; r < R; ++r)
                idx_nxt[r] = *reinterpret_cast<const int4*>(
                    widx + (size_t)(o0 + r) * IN_F + c + 4 * BLOCK);
        }

        // gather 16 weights from LDS (same-entry lanes broadcast; ~free)
        const int gcol = (c >> 7) * 16;
        float w[R][4];
#pragma unroll
        for (int r = 0; r < R; ++r) {
            const float* lr = lutS + r * (NGR * 16) + gcol;
            w[r][0] = lr[idx_cur[r].x];
            w[r][1] = lr[idx_cur[r].y];
            w[r][2] = lr[idx_cur[r].z];
            w[r][3] = lr[idx_cur[r].w];
        }

        // batch loop split in two chunks of 4 to halve live x registers
#pragma unroll 1
        for (int mb = 0; mb < NBATCH; mb += 4) {
            float4 xv[4];
#pragma unroll
            for (int mm = 0; mm < 4; ++mm)
                xv[mm] = *reinterpret_cast<const float4*>(x + (mb + mm) * IN_F + c);
#pragma unroll
            for (int mm = 0; mm < 4; ++mm)
#pragma unroll
                for (int r = 0; r < R; ++r) {
                    float a = acc[r][mb + mm];
                    a = fmaf(w[r][0], xv[mm].x, a);
                    a = fmaf(w[r][1], xv[mm].y, a);
                    a = fmaf(w[r][2], xv[mm].z, a);
                    a = fmaf(w[r][3], xv[mm].w, a);
                    acc[r][mb + mm] = a;
                }
        }

#pragma unroll
        for (int r = 0; r < R; ++r) idx_cur[r] = idx_nxt[r];
    }

    // reduce 256 threads' partials
#pragma unroll
    for (int r = 0; r < R; ++r)
#pragma unroll
        for (int m = 0; m < NBATCH; ++m) {
            float v = acc[r][m];
#pragma unroll
            for (int off = 32; off >= 1; off >>= 1)
                v += __shfl_xor(v, off, 64);
            acc[r][m] = v;
        }

    const int wave = tid >> 6;
    const int lane = tid & 63;
    if (lane == 0) {
#pragma unroll
        for (int r = 0; r < R; ++r)
#pragma unroll
            for (int m = 0; m < NBATCH; ++m)
                red[wave][r * NBATCH + m] = acc[r][m];
    }
    __syncthreads();

    if (tid < R * NBATCH) {
        const int r = tid >> 3;
        const int m = tid & 7;
        float total = red[0][tid] + red[1][tid] + red[2][tid] + red[3][tid];
        out[(size_t)m * OUT_F + (o0 + r)] = total + bias[o0 + r];
    }
}

extern "C" void kernel_launch(void* const* d_in, const int* in_sizes, int n_in,
                              void* d_out, int out_size, void* d_ws, size_t ws_size,
                              hipStream_t stream) {
    const float* x    = (const float*)d_in[0];
    const int*   widx = (const int*)d_in[1];
    const float* lut  = (const float*)d_in[2];
    const float* bias = (const float*)d_in[3];
    float* out = (float*)d_out;

    pal_linear_kernel<<<OUT_F / R, BLOCK, 0, stream>>>(x, widx, lut, bias, out);
}

// Round 6
// 267.547 us; speedup vs baseline: 1.4363x; 1.4363x over previous
//
#include <hip/hip_runtime.h>

#define OUT_F 11008
#define IN_F  4096
#define NBATCH 8
#define R 4                     // output rows per block
#define BLOCK 256
#define NGR 32                  // groups per row = IN_F/128
#define KITERS (IN_F / (4 * BLOCK))   // 4: each thread covers 4 columns per k-iter

// NOTE: no min-waves clamp. (256,4)'s 128-VGPR cap forced spills (R4),
// and a runtime-indexed acc[] put accumulators in scratch entirely
// (R5: VGPR=48, WRITE_SIZE=404MB). All loops touching local arrays are
// fully unrolled -> static indices -> registers.
__global__ __launch_bounds__(BLOCK) void pal_linear_kernel(
    const float* __restrict__ x,        // [8, 4096]
    const int*   __restrict__ widx,     // [11008*4096] in [0,16)
    const float* __restrict__ lut,      // [352256, 16] f32 on device
    const float* __restrict__ bias,     // [11008]
    float* __restrict__ out)            // [8, 11008]
{
    __shared__ float lutS[R * NGR * 16];            // 8 KB contiguous slice
    __shared__ float red[BLOCK / 64][R * NBATCH];

    const int tid = threadIdx.x;
    const int o0  = blockIdx.x * R;

    // stage this block's LUT slice (2048 consecutive floats) into LDS
    {
        const float4* src = reinterpret_cast<const float4*>(lut + (size_t)o0 * NGR * 16);
        float4* dst = reinterpret_cast<float4*>(lutS);
#pragma unroll
        for (int i = 0; i < (R * NGR * 16 / 4) / BLOCK; ++i)   // 2 iters
            dst[tid + i * BLOCK] = src[tid + i * BLOCK];
    }
    __syncthreads();

    float acc[R][NBATCH];
#pragma unroll
    for (int r = 0; r < R; ++r)
#pragma unroll
        for (int m = 0; m < NBATCH; ++m) acc[r][m] = 0.0f;

    // 1-deep software pipeline on the 180 MB index stream
    int4 idx_cur[R], idx_nxt[R];
#pragma unroll
    for (int r = 0; r < R; ++r)
        idx_cur[r] = *reinterpret_cast<const int4*>(widx + (size_t)(o0 + r) * IN_F + 4 * tid);

#pragma unroll 1
    for (int k = 0; k < KITERS; ++k) {
        const int c = 4 * (tid + BLOCK * k);

        if (k + 1 < KITERS) {
#pragma unroll
            for (int r = 0; r < R; ++r)
                idx_nxt[r] = *reinterpret_cast<const int4*>(
                    widx + (size_t)(o0 + r) * IN_F + c + 4 * BLOCK);
        }

        // gather 16 weights from LDS (static indices into w[])
        const int gcol = (c >> 7) * 16;
        float w[R][4];
#pragma unroll
        for (int r = 0; r < R; ++r) {
            const float* lr = lutS + r * (NGR * 16) + gcol;
            w[r][0] = lr[idx_cur[r].x];
            w[r][1] = lr[idx_cur[r].y];
            w[r][2] = lr[idx_cur[r].z];
            w[r][3] = lr[idx_cur[r].w];
        }

        // batch loop FULLY unrolled: acc indices compile-time
#pragma unroll
        for (int m = 0; m < NBATCH; ++m) {
            const float4 xm = *reinterpret_cast<const float4*>(x + m * IN_F + c);
#pragma unroll
            for (int r = 0; r < R; ++r) {
                float a = acc[r][m];
                a = fmaf(w[r][0], xm.x, a);
                a = fmaf(w[r][1], xm.y, a);
                a = fmaf(w[r][2], xm.z, a);
                a = fmaf(w[r][3], xm.w, a);
                acc[r][m] = a;
            }
        }

#pragma unroll
        for (int r = 0; r < R; ++r) idx_cur[r] = idx_nxt[r];
    }

    // reduce 256 threads' partials
#pragma unroll
    for (int r = 0; r < R; ++r)
#pragma unroll
        for (int m = 0; m < NBATCH; ++m) {
            float v = acc[r][m];
#pragma unroll
            for (int off = 32; off >= 1; off >>= 1)
                v += __shfl_xor(v, off, 64);
            acc[r][m] = v;
        }

    const int wave = tid >> 6;
    const int lane = tid & 63;
    if (lane == 0) {
#pragma unroll
        for (int r = 0; r < R; ++r)
#pragma unroll
            for (int m = 0; m < NBATCH; ++m)
                red[wave][r * NBATCH + m] = acc[r][m];
    }
    __syncthreads();

    if (tid < R * NBATCH) {
        const int r = tid >> 3;
        const int m = tid & 7;
        float total = red[0][tid] + red[1][tid] + red[2][tid] + red[3][tid];
        out[(size_t)m * OUT_F + (o0 + r)] = total + bias[o0 + r];
    }
}

extern "C" void kernel_launch(void* const* d_in, const int* in_sizes, int n_in,
                              void* d_out, int out_size, void* d_ws, size_t ws_size,
                              hipStream_t stream) {
    const float* x    = (const float*)d_in[0];
    const int*   widx = (const int*)d_in[1];
    const float* lut  = (const float*)d_in[2];
    const float* bias = (const float*)d_in[3];
    float* out = (float*)d_out;

    pal_linear_kernel<<<OUT_F / R, BLOCK, 0, stream>>>(x, widx, lut, bias, out);
}

// Round 7
// 266.811 us; speedup vs baseline: 1.4403x; 1.0028x over previous
//
#include <hip/hip_runtime.h>

#define OUT_F 11008
#define IN_F  4096
#define NBATCH 8
#define R 4                      // output rows per wave
#define BLOCK 64                 // ONE wave per block: no barriers, no cross-wave reduce
#define NGR 32                   // groups per row = IN_F/128
#define KITERS (IN_F / (4 * BLOCK))   // 16 iters: lane covers 4 cols per iter

// One wave owns 4 output rows x all 4096 columns. 16-iter streaming loop with
// 1-deep idx prefetch. x loads issued BEFORE idx prefetch each iter: vmcnt is
// in-order, so FMAs wait vmcnt(4) (x done) while the 4 HBM idx loads stay in
// flight (R6 had prefetch-first -> vmcnt(0) drained it every iter).
__global__ __launch_bounds__(BLOCK) void pal_linear_kernel(
    const float* __restrict__ x,        // [8, 4096]
    const int*   __restrict__ widx,     // [11008*4096] in [0,16)
    const float* __restrict__ lut,      // [352256, 16] f32 on device
    const float* __restrict__ bias,     // [11008]
    float* __restrict__ out)            // [8, 11008]
{
    __shared__ float lutS[R * NGR * 16];   // 8 KB wave-private slice

    const int tid = threadIdx.x;           // lane 0..63
    const int o0  = blockIdx.x * R;

    // stage the tile's LUT slice: 2048 consecutive floats = 64 lanes x 8 float4
    {
        const float4* src = reinterpret_cast<const float4*>(lut + (size_t)o0 * NGR * 16);
        float4* dst = reinterpret_cast<float4*>(lutS);
#pragma unroll
        for (int i = 0; i < (R * NGR * 16 / 4) / BLOCK; ++i)   // 8 iters
            dst[tid + i * BLOCK] = src[tid + i * BLOCK];
    }
    __syncthreads();   // single wave: compiles to waitcnt, cheap

    float acc[R][NBATCH];
#pragma unroll
    for (int r = 0; r < R; ++r)
#pragma unroll
        for (int m = 0; m < NBATCH; ++m) acc[r][m] = 0.0f;

    int4 idx_cur[R], idx_nxt[R];
#pragma unroll
    for (int r = 0; r < R; ++r)
        idx_cur[r] = *reinterpret_cast<const int4*>(widx + (size_t)(o0 + r) * IN_F + 4 * tid);

#pragma unroll 1
    for (int k = 0; k < KITERS; ++k) {
        const int c = 4 * (tid + BLOCK * k);

        // 1) x loads first (L2-fast, retire early in the in-order vmcnt queue)
        float4 xv[NBATCH];
#pragma unroll
        for (int m = 0; m < NBATCH; ++m)
            xv[m] = *reinterpret_cast<const float4*>(x + m * IN_F + c);

        // 2) then the HBM idx prefetch — rides through the FMAs
        if (k + 1 < KITERS) {
#pragma unroll
            for (int r = 0; r < R; ++r)
                idx_nxt[r] = *reinterpret_cast<const int4*>(
                    widx + (size_t)(o0 + r) * IN_F + c + 4 * BLOCK);
        }

        // 3) LDS gathers with the current (already-arrived) indices
        const int gcol = (c >> 7) * 16;    // group-within-row * 16
        float w[R][4];
#pragma unroll
        for (int r = 0; r < R; ++r) {
            const float* lr = lutS + r * (NGR * 16) + gcol;
            w[r][0] = lr[idx_cur[r].x];
            w[r][1] = lr[idx_cur[r].y];
            w[r][2] = lr[idx_cur[r].z];
            w[r][3] = lr[idx_cur[r].w];
        }

        // 4) FMAs (fully unrolled -> all arrays stay in registers)
#pragma unroll
        for (int m = 0; m < NBATCH; ++m)
#pragma unroll
            for (int r = 0; r < R; ++r) {
                float a = acc[r][m];
                a = fmaf(w[r][0], xv[m].x, a);
                a = fmaf(w[r][1], xv[m].y, a);
                a = fmaf(w[r][2], xv[m].z, a);
                a = fmaf(w[r][3], xv[m].w, a);
                acc[r][m] = a;
            }

#pragma unroll
        for (int r = 0; r < R; ++r) idx_cur[r] = idx_nxt[r];
    }

    // full-wave butterfly: every acc[r][m] becomes the row-sum in all lanes
#pragma unroll
    for (int r = 0; r < R; ++r)
#pragma unroll
        for (int m = 0; m < NBATCH; ++m) {
            float v = acc[r][m];
#pragma unroll
            for (int off = 32; off >= 1; off >>= 1)
                v += __shfl_xor(v, off, 64);
            acc[r][m] = v;
        }

    // static select (no runtime indexing into register arrays — R5 lesson):
    // lane t = r*8+m writes out[m][o0+r]
    float v = 0.0f;
#pragma unroll
    for (int r = 0; r < R; ++r)
#pragma unroll
        for (int m = 0; m < NBATCH; ++m)
            if (tid == r * NBATCH + m) v = acc[r][m];

    if (tid < R * NBATCH) {
        const int r = tid >> 3;
        const int m = tid & 7;
        out[(size_t)m * OUT_F + (o0 + r)] = v + bias[o0 + r];
    }
}

extern "C" void kernel_launch(void* const* d_in, const int* in_sizes, int n_in,
                              void* d_out, int out_size, void* d_ws, size_t ws_size,
                              hipStream_t stream) {
    const float* x    = (const float*)d_in[0];
    const int*   widx = (const int*)d_in[1];
    const float* lut  = (const float*)d_in[2];
    const float* bias = (const float*)d_in[3];
    float* out = (float*)d_out;

    pal_linear_kernel<<<OUT_F / R, BLOCK, 0, stream>>>(x, widx, lut, bias, out);
}